// Round 12
// baseline (164.802 us; speedup 1.0000x reference)
//
#include <hip/hip_runtime.h>
#include <hip/hip_bf16.h>

// Problem constants
#define BT 2048   // batch
#define DD 512    // input dim
#define HH 512    // hidden dim
#define EE 32     // experts
#define KK 4      // top-k
#define CHN 32    // confidence hidden
#define MAXCH 160 // max 64-row chunks: 8192/64 + 32

// fused prep block ranges (clustered: long gate blocks first = LPT schedule)
#define NB_GH 512
#define NB_CVT 512
#define NB_TRWC 256
#define NB_TRW 2048
#define NB_PREP (NB_GH + NB_CVT + NB_TRWC + NB_TRW)

typedef unsigned int u32;
typedef unsigned short u16;
typedef __attribute__((ext_vector_type(8))) short short8;
typedef __attribute__((ext_vector_type(4))) float f32x4;
typedef __attribute__((ext_vector_type(2))) u32 u32x2;
typedef __attribute__((ext_vector_type(4))) u32 u32x4;

__device__ inline u16 f2bf(float f) {  // RNE float->bf16
  u32 u = __builtin_bit_cast(u32, f);
  u32 r = (u + 0x7FFFu + ((u >> 16) & 1u)) >> 16;
  return (u16)r;
}
__device__ inline u32 pack2bf(float a, float b) {
  return (u32)f2bf(a) | ((u32)f2bf(b) << 16);
}
__device__ inline void gload_lds16(const u32* g, u32* l) {
  __builtin_amdgcn_global_load_lds((const __attribute__((address_space(1))) u32*)g,
                                   (__attribute__((address_space(3))) u32*)l, 16, 0, 0);
}

// ---------------------------------------------------------------------------
// Fused prep: gate_hidden | cvt_x | tr_wc | tr_w. Clustered order (gate
// first). Gate branch is LDS-FREE: each 32-lane group owns 2 x-rows and
// broadcasts via __shfl — kernel has zero LDS so streaming blocks reach
// 6 blocks/CU instead of 4.
// ---------------------------------------------------------------------------
__global__ __launch_bounds__(256, 6)
void k_prep(const float* __restrict__ x, const float* __restrict__ W1,
            const float* __restrict__ W2, const float* __restrict__ Wc1,
            const float* __restrict__ Wg1, const float* __restrict__ bg1,
            u16* __restrict__ xb, u32* __restrict__ img,
            u32* __restrict__ img_c, float* __restrict__ h) {
  const int bx = blockIdx.x;
  const int tid = threadIdx.x;
  if (bx < NB_GH) {
    // ---- gate_hidden: h = relu(x @ Wg1 + bg1), fp32, LDS-free ----
    const int row0 = (bx >> 2) * 16;
    const int cb = (bx & 3) * 128;
    const int cg = tid & 31, rg = tid >> 5;   // 8 groups x 2 rows
    const int n0 = cb + cg * 4;
    const int r0 = row0 + rg * 2, r1 = r0 + 1;
    float4 a0 = {0.f, 0.f, 0.f, 0.f}, a1 = {0.f, 0.f, 0.f, 0.f};
    for (int k0 = 0; k0 < DD; k0 += 32) {
      float xa = x[(size_t)r0 * DD + k0 + cg];
      float xbv = x[(size_t)r1 * DD + k0 + cg];
#pragma unroll
      for (int u0 = 0; u0 < 32; u0 += 8) {
        float4 wv[8];
#pragma unroll
        for (int u = 0; u < 8; ++u)
          wv[u] = *reinterpret_cast<const float4*>(
              &Wg1[(size_t)(k0 + u0 + u) * HH + n0]);
#pragma unroll
        for (int u = 0; u < 8; ++u) {
          float xav = __shfl(xa, u0 + u, 32);
          float xbb = __shfl(xbv, u0 + u, 32);
          a0.x = fmaf(xav, wv[u].x, a0.x);
          a0.y = fmaf(xav, wv[u].y, a0.y);
          a0.z = fmaf(xav, wv[u].z, a0.z);
          a0.w = fmaf(xav, wv[u].w, a0.w);
          a1.x = fmaf(xbb, wv[u].x, a1.x);
          a1.y = fmaf(xbb, wv[u].y, a1.y);
          a1.z = fmaf(xbb, wv[u].z, a1.z);
          a1.w = fmaf(xbb, wv[u].w, a1.w);
        }
      }
    }
    float4 bb = *reinterpret_cast<const float4*>(&bg1[n0]);
    float4 o0, o1;
    o0.x = fmaxf(a0.x + bb.x, 0.f); o0.y = fmaxf(a0.y + bb.y, 0.f);
    o0.z = fmaxf(a0.z + bb.z, 0.f); o0.w = fmaxf(a0.w + bb.w, 0.f);
    o1.x = fmaxf(a1.x + bb.x, 0.f); o1.y = fmaxf(a1.y + bb.y, 0.f);
    o1.z = fmaxf(a1.z + bb.z, 0.f); o1.w = fmaxf(a1.w + bb.w, 0.f);
    *reinterpret_cast<float4*>(&h[(size_t)r0 * HH + n0]) = o0;
    *reinterpret_cast<float4*>(&h[(size_t)r1 * HH + n0]) = o1;
  } else if (bx < NB_GH + NB_CVT) {
    // ---- cvt_x: x fp32 -> bf16 ----
    int gid = (bx - NB_GH) * 256 + tid;
    const float4* src = reinterpret_cast<const float4*>(x) + (size_t)gid * 2;
    float4 a = src[0], b = src[1];
    u32x4 o = { pack2bf(a.x, a.y), pack2bf(a.z, a.w),
                pack2bf(b.x, b.y), pack2bf(b.z, b.w) };
    reinterpret_cast<u32x4*>(xb)[gid] = o;
  } else if (bx < NB_GH + NB_CVT + NB_TRWC) {
    // ---- tr_wc: Wc1 -> bf16 k-major fraglet image ----
    int idx = (bx - (NB_GH + NB_CVT)) * 2 + (tid >> 7);
    int e = idx >> 4, s = idx & 15;
    int t127 = tid & 127;
    int q = t127 >> 5, col = t127 & 31;
    const float* W = Wc1 + (size_t)e * DD * CHN;
    float v[8];
#pragma unroll
    for (int j = 0; j < 8; ++j)
      v[j] = W[(size_t)(s * 32 + q * 8 + j) * CHN + col];
    u32x4 fr = { pack2bf(v[0], v[1]), pack2bf(v[2], v[3]),
                 pack2bf(v[4], v[5]), pack2bf(v[6], v[7]) };
    *reinterpret_cast<u32x4*>(img_c + ((size_t)e * 16 + s) * 512 + q * 128 + col * 4) = fr;
  } else {
    // ---- tr_w: W1/W2 -> k-major bf16 fraglet images ----
    int u = bx - (NB_GH + NB_CVT + NB_TRWC);
    int z = u >> 5;
    int s = (u >> 1) & 15;
    int n = (u & 1) * 256 + tid;
    const float* W = (z < EE) ? (W1 + (size_t)z * DD * HH)
                              : (W2 + (size_t)(z - EE) * HH * DD);
    float v[32];
#pragma unroll
    for (int k = 0; k < 32; k++)
      v[k] = W[(size_t)(s * 32 + k) * 512 + n];
    int nc = n >> 7, coll = n & 127;
    u32* ob = img + ((size_t)(z * 4 + nc) * 16 + s) * 2048 + coll * 4;
#pragma unroll
    for (int g = 0; g < 4; g++) {
      u32x4 fr = { pack2bf(v[g * 8 + 0], v[g * 8 + 1]),
                   pack2bf(v[g * 8 + 2], v[g * 8 + 3]),
                   pack2bf(v[g * 8 + 4], v[g * 8 + 5]),
                   pack2bf(v[g * 8 + 6], v[g * 8 + 7]) };
      *reinterpret_cast<u32x4*>(ob + g * 512) = fr;
    }
  }
}

// ---------------------------------------------------------------------------
// Gating logits + softmax + top-4. 8 tokens/block, 256 thr. NO atomics:
// writes wts[B][E] and topi[B][K] only; tlist built by k_build.
// ---------------------------------------------------------------------------
__global__ __launch_bounds__(256)
void k_gate_route(const float* __restrict__ h, const float* __restrict__ Wg2,
                  const float* __restrict__ bg2, float* __restrict__ wts,
                  int* __restrict__ topi) {
  __shared__ float wg2s[HH * EE];  // 64 KB, k-major [512][32]
  __shared__ float hb[8][HH];      // 16 KB
  const int tid = threadIdx.x;
  const int t0 = blockIdx.x * 8;
#pragma unroll
  for (int i = 0; i < 16; ++i) {
    int idx = tid + i * 256;       // float4 index, 4096 total
    reinterpret_cast<float4*>(wg2s)[idx] =
        reinterpret_cast<const float4*>(Wg2)[idx];
  }
  for (int idx = tid; idx < 8 * 128; idx += 256) {
    int m = idx >> 7, j = idx & 127;
    *reinterpret_cast<float4*>(&hb[m][4 * j]) =
        *reinterpret_cast<const float4*>(&h[(size_t)(t0 + m) * HH + 4 * j]);
  }
  __syncthreads();
  const int lane = tid & 63, wv = tid >> 6;
  const int e = lane & 31, th = lane >> 5;
  const int lt = wv * 2 + th;          // local token 0..7
  const int t = t0 + lt;
  float ac[4] = {0.f, 0.f, 0.f, 0.f};
  for (int k0 = 0; k0 < HH; k0 += 8) {
    float4 h0 = *reinterpret_cast<const float4*>(&hb[lt][k0]);
    float4 h1 = *reinterpret_cast<const float4*>(&hb[lt][k0 + 4]);
    float hv[8] = {h0.x, h0.y, h0.z, h0.w, h1.x, h1.y, h1.z, h1.w};
#pragma unroll
    for (int u = 0; u < 8; ++u)
      ac[u & 3] = fmaf(hv[u], wg2s[(k0 + u) * EE + e], ac[u & 3]);
  }
  float logit = ((ac[0] + ac[1]) + (ac[2] + ac[3])) + bg2[e];
  // softmax over the 32-lane group
  float mx = logit;
#pragma unroll
  for (int m = 16; m >= 1; m >>= 1) mx = fmaxf(mx, __shfl_xor(mx, m, 32));
  float ex = expf(logit - mx);
  float sm = ex;
#pragma unroll
  for (int m = 16; m >= 1; m >>= 1) sm += __shfl_xor(sm, m, 32);
  float w = ex / sm;
  wts[(size_t)t * EE + e] = w;
  float wcur = w;
  for (int j = 0; j < KK; j++) {
    float v = wcur;
    int vi = e;
#pragma unroll
    for (int m = 16; m >= 1; m >>= 1) {
      float ov = __shfl_xor(v, m, 32);
      int oi = __shfl_xor(vi, m, 32);
      if (ov > v || (ov == v && oi < vi)) { v = ov; vi = oi; }
    }
    if (e == 0) topi[(t << 2) | j] = vi;
    if (e == vi) wcur = -1.f;
  }
}

// ---------------------------------------------------------------------------
// Build routing lists + chunk tables from topi. One block, 1024 thr.
// ---------------------------------------------------------------------------
__global__ __launch_bounds__(1024)
void k_build(const int* __restrict__ topi, int* __restrict__ cnt,
             int* __restrict__ tlist, int* __restrict__ chunk2e,
             int* __restrict__ chunkloc) {
  __shared__ int lcnt[EE];
  const int tid = threadIdx.x;
  if (tid < EE) lcnt[tid] = 0;
  __syncthreads();
  for (int i = tid; i < BT * KK; i += 1024) {
    int e = topi[i];
    int pos = atomicAdd(&lcnt[e], 1);
    tlist[(size_t)e * BT + pos] = i;   // ent == (t<<2)|j == i
  }
  __syncthreads();
  if (tid < EE) {
    int e = tid;
    cnt[e] = lcnt[e];
    int off = 0, tot = 0;
    for (int j = 0; j < EE; ++j) {
      int nj = (lcnt[j] + 63) >> 6;
      if (j < e) off += nj;
      tot += nj;
    }
    int myn = (lcnt[e] + 63) >> 6;
    for (int j = 0; j < myn; ++j) {
      chunk2e[off + j] = e; chunkloc[off + j] = j;
    }
    for (int idx = tot + e; idx < MAXCH; idx += EE) {
      chunk2e[idx] = -1; chunkloc[idx] = 0;
    }
  }
}

// XCD-affinity chunk remap.
__device__ inline int remap_chunk(int bx) {
  return (bx & 7) * (MAXCH / 8) + (bx >> 3);
}

// ---------------------------------------------------------------------------
// GEMM1 (grouped, swapped): hidT = W1T(512h x 512k) . xT(512k x 64t).
// ---------------------------------------------------------------------------
__global__ __launch_bounds__(256)
void k_gemm1(const u16* __restrict__ xb, const u32* __restrict__ img,
             const float* __restrict__ b1, const int* __restrict__ cnt,
             const int* __restrict__ tlist, const int* __restrict__ chunk2e,
             const int* __restrict__ chunkloc, u32* __restrict__ hid) {
  __shared__ u32 stg[2][4096];   // 2 x 16 KB
  __shared__ int tkl[64];
  const int c = remap_chunk(blockIdx.x);
  const int e = chunk2e[c];
  if (e < 0) return;
  const int hc = blockIdx.y;
  const int loc = chunkloc[c];
  const int nt = cnt[e];
  const int tid = threadIdx.x;
  const int w = tid >> 6, lane = tid & 63;
  const int l15 = lane & 15, q = lane >> 4;
  const int wm = w & 1, wn = w >> 1;

  const u32* imgb = img + ((size_t)(e * 4 + hc) * 16) * 2048;
  auto stage = [&](int st, u32* dst) {
    const u32* src = imgb + st * 4096;
#pragma unroll
    for (int i = 0; i < 4; i++)
      gload_lds16(src + tid * 4 + i * 1024, dst + tid * 4 + i * 1024);
  };

  stage(0, stg[0]);
  if (tid < 64) {
    int i = min(loc * 64 + tid, nt - 1);
    tkl[tid] = tlist[(size_t)e * BT + i] >> 2;
  }
  __syncthreads();   // tkl visible + stage(0) drained

  const int t0 = tkl[wn * 32 + l15];
  const int t1 = tkl[wn * 32 + 16 + l15];
  auto ldb = [&](int t, int st, int ss) {
    return *reinterpret_cast<const short8*>(
        xb + (size_t)t * 512 + st * 64 + ss * 32 + q * 8);
  };

  f32x4 acc[4][2];
#pragma unroll
  for (int a = 0; a < 4; a++)
#pragma unroll
    for (int b = 0; b < 2; b++) acc[a][b] = {0.f, 0.f, 0.f, 0.f};

  short8 bfr[2][2];  // [nf][ss]
  bfr[0][0] = ldb(t0, 0, 0); bfr[0][1] = ldb(t0, 0, 1);
  bfr[1][0] = ldb(t1, 0, 0); bfr[1][1] = ldb(t1, 0, 1);

  for (int st = 0; st < 8; ++st) {
    const u32* cur = stg[st & 1];
    short8 nb[2][2];
    if (st < 7) {
      stage(st + 1, stg[(st + 1) & 1]);
      nb[0][0] = ldb(t0, st + 1, 0); nb[0][1] = ldb(t0, st + 1, 1);
      nb[1][0] = ldb(t1, st + 1, 0); nb[1][1] = ldb(t1, st + 1, 1);
    }
#pragma unroll
    for (int ss = 0; ss < 2; ++ss) {
#pragma unroll
      for (int mf = 0; mf < 4; ++mf) {
        int col = wm * 64 + mf * 16 + l15;
        short8 af = *reinterpret_cast<const short8*>(
            cur + ss * 2048 + q * 512 + col * 4);
        acc[mf][0] = __builtin_amdgcn_mfma_f32_16x16x32_bf16(af, bfr[0][ss], acc[mf][0], 0, 0, 0);
        acc[mf][1] = __builtin_amdgcn_mfma_f32_16x16x32_bf16(af, bfr[1][ss], acc[mf][1], 0, 0, 0);
      }
    }
    __syncthreads();   // next stage drained; buffers safe to swap
    if (st < 7) {
      bfr[0][0] = nb[0][0]; bfr[0][1] = nb[0][1];
      bfr[1][0] = nb[1][0]; bfr[1][1] = nb[1][1];
    }
  }

  // epilogue: bias + relu + pack bf16 -> hid[prow][h]
  const float* b1e = b1 + (size_t)e * HH;
#pragma unroll
  for (int mf = 0; mf < 4; ++mf) {
    int h0 = hc * 128 + wm * 64 + mf * 16 + q * 4;
    float4 bb = *reinterpret_cast<const float4*>(b1e + h0);
#pragma unroll
    for (int nf = 0; nf < 2; ++nf) {
      int local = wn * 32 + nf * 16 + l15;
      int prow = c * 64 + local;
      float v0 = fmaxf(acc[mf][nf].x + bb.x, 0.f);
      float v1 = fmaxf(acc[mf][nf].y + bb.y, 0.f);
      float v2 = fmaxf(acc[mf][nf].z + bb.z, 0.f);
      float v3 = fmaxf(acc[mf][nf].w + bb.w, 0.f);
      u32x2 pk = { pack2bf(v0, v1), pack2bf(v2, v3) };
      *reinterpret_cast<u32x2*>(hid + (size_t)prow * 256 + (h0 >> 1)) = pk;
    }
  }
}

// ---------------------------------------------------------------------------
// GEMM2 (grouped, swapped): oT = W2T(512d x 512h) . hidT(512h x 64t).
// ---------------------------------------------------------------------------
__global__ __launch_bounds__(256)
void k_gemm2(const u32* __restrict__ hid, const u32* __restrict__ img,
             const float* __restrict__ b2, const int* __restrict__ cnt,
             const int* __restrict__ tlist, const int* __restrict__ chunk2e,
             const int* __restrict__ chunkloc, float* __restrict__ o_p) {
  __shared__ u32 stg[2][4096];
  __shared__ int tke[64];
  const int c = remap_chunk(blockIdx.x);
  const int e = chunk2e[c];
  if (e < 0) return;
  const int dc = blockIdx.y;
  const int loc = chunkloc[c];
  const int nt = cnt[e];
  const int tid = threadIdx.x;
  const int w = tid >> 6, lane = tid & 63;
  const int l15 = lane & 15, q = lane >> 4;
  const int wm = w & 1, wn = w >> 1;
  const int rows_c = min(64, nt - loc * 64);

  const u32* imgb = img + ((size_t)((EE + e) * 4 + dc) * 16) * 2048;
  auto stage = [&](int st, u32* dst) {
    const u32* src = imgb + st * 4096;
#pragma unroll
    for (int i = 0; i < 4; i++)
      gload_lds16(src + tid * 4 + i * 1024, dst + tid * 4 + i * 1024);
  };

  stage(0, stg[0]);
  if (tid < 64) {
    int i = min(loc * 64 + tid, nt - 1);
    tke[tid] = tlist[(size_t)e * BT + i];
  }
  __syncthreads();

  const u16* hid16 = (const u16*)hid;
  const int pr0 = c * 64 + wn * 32 + l15;
  const int pr1 = pr0 + 16;
  auto ldb = [&](int pr, int st, int ss) {
    return *reinterpret_cast<const short8*>(
        hid16 + (size_t)pr * 512 + st * 64 + ss * 32 + q * 8);
  };

  f32x4 acc[4][2];
#pragma unroll
  for (int a = 0; a < 4; a++)
#pragma unroll
    for (int b = 0; b < 2; b++) acc[a][b] = {0.f, 0.f, 0.f, 0.f};

  short8 bfr[2][2];
  bfr[0][0] = ldb(pr0, 0, 0); bfr[0][1] = ldb(pr0, 0, 1);
  bfr[1][0] = ldb(pr1, 0, 0); bfr[1][1] = ldb(pr1, 0, 1);

  for (int st = 0; st < 8; ++st) {
    const u32* cur = stg[st & 1];
    short8 nb[2][2];
    if (st < 7) {
      stage(st + 1, stg[(st + 1) & 1]);
      nb[0][0] = ldb(pr0, st + 1, 0); nb[0][1] = ldb(pr0, st + 1, 1);
      nb[1][0] = ldb(pr1, st + 1, 0); nb[1][1] = ldb(pr1, st + 1, 1);
    }
#pragma unroll
    for (int ss = 0; ss < 2; ++ss) {
#pragma unroll
      for (int mf = 0; mf < 4; ++mf) {
        int col = wm * 64 + mf * 16 + l15;
        short8 af = *reinterpret_cast<const short8*>(
            cur + ss * 2048 + q * 512 + col * 4);
        acc[mf][0] = __builtin_amdgcn_mfma_f32_16x16x32_bf16(af, bfr[0][ss], acc[mf][0], 0, 0, 0);
        acc[mf][1] = __builtin_amdgcn_mfma_f32_16x16x32_bf16(af, bfr[1][ss], acc[mf][1], 0, 0, 0);
      }
    }
    __syncthreads();
    if (st < 7) {
      bfr[0][0] = nb[0][0]; bfr[0][1] = nb[0][1];
      bfr[1][0] = nb[1][0]; bfr[1][1] = nb[1][1];
    }
  }

  // epilogue: bias + scatter fp32 to o_p[(t*K+slot)*D + d] (skip pad rows)
  const float* b2e = b2 + (size_t)e * DD;
#pragma unroll
  for (int mf = 0; mf < 4; ++mf) {
    int d0 = dc * 128 + wm * 64 + mf * 16 + q * 4;
    float4 bb = *reinterpret_cast<const float4*>(b2e + d0);
#pragma unroll
    for (int nf = 0; nf < 2; ++nf) {
      int local = wn * 32 + nf * 16 + l15;
      if (local < rows_c) {
        int ent = tke[local];
        int t = ent >> 2, sl = ent & 3;
        float4 v;
        v.x = acc[mf][nf].x + bb.x;
        v.y = acc[mf][nf].y + bb.y;
        v.z = acc[mf][nf].z + bb.z;
        v.w = acc[mf][nf].w + bb.w;
        *reinterpret_cast<float4*>(&o_p[((size_t)t * KK + sl) * DD + d0]) = v;
      }
    }
  }
}

// ---------------------------------------------------------------------------
// Confidence via MFMA. One block per 64-token chunk, 256 thr (4 waves).
// ---------------------------------------------------------------------------
__global__ __launch_bounds__(256)
void k_conf2(const float* __restrict__ o_p, const u32* __restrict__ img_c,
             const float* __restrict__ bc1, const float* __restrict__ Wc2,
             const float* __restrict__ bc2, const float* __restrict__ wts,
             const int* __restrict__ cnt, const int* __restrict__ tlist,
             const int* __restrict__ chunk2e, const int* __restrict__ chunkloc,
             float* __restrict__ cw) {
  __shared__ u32 stg[8192];   // 32 KB: full Wc1e image (16 steps x 512 u32)
  __shared__ int tke[64];
  const int c = remap_chunk(blockIdx.x);
  const int e = chunk2e[c];
  if (e < 0) return;
  const int loc = chunkloc[c];
  const int nt = cnt[e];
  const int tid = threadIdx.x;
  const int w = tid >> 6, lane = tid & 63;
  const int l15 = lane & 15, q = lane >> 4;

  const u32* src = img_c + (size_t)e * 16 * 512;
#pragma unroll
  for (int i = 0; i < 8; ++i)
    gload_lds16(src + tid * 4 + i * 1024, stg + tid * 4 + i * 1024);
  if (tid < 64) {
    int i = min(loc * 64 + tid, nt - 1);
    tke[tid] = tlist[(size_t)e * BT + i];
  }
  __syncthreads();   // stage drained + tke visible

  const int rows_c = min(64, nt - loc * 64);
  const int local = w * 16 + l15;
  const int ent = tke[local];
  const float* orow = o_p + (size_t)ent * DD;

  f32x4 acc0 = {0.f, 0.f, 0.f, 0.f}, acc1 = {0.f, 0.f, 0.f, 0.f};
#pragma unroll
  for (int st = 0; st < 16; ++st) {
    float4 f0 = *reinterpret_cast<const float4*>(orow + st * 32 + q * 8);
    float4 f1 = *reinterpret_cast<const float4*>(orow + st * 32 + q * 8 + 4);
    u32x4 bp = { pack2bf(f0.x, f0.y), pack2bf(f0.z, f0.w),
                 pack2bf(f1.x, f1.y), pack2bf(f1.z, f1.w) };
    short8 bfrag = __builtin_bit_cast(short8, bp);
    short8 af0 = *reinterpret_cast<const short8*>(
        stg + st * 512 + q * 128 + l15 * 4);
    short8 af1 = *reinterpret_cast<const short8*>(
        stg + st * 512 + q * 128 + (16 + l15) * 4);
    acc0 = __builtin_amdgcn_mfma_f32_16x16x32_bf16(af0, bfrag, acc0, 0, 0, 0);
    acc1 = __builtin_amdgcn_mfma_f32_16x16x32_bf16(af1, bfrag, acc1, 0, 0, 0);
  }

  float part = 0.f;
#pragma unroll
  for (int i = 0; i < 4; ++i) {
    int ch0 = q * 4 + i, ch1 = 16 + q * 4 + i;
    float h0 = fmaxf(acc0[i] + bc1[(size_t)e * CHN + ch0], 0.f);
    float h1 = fmaxf(acc1[i] + bc1[(size_t)e * CHN + ch1], 0.f);
    part = fmaf(h0, Wc2[(size_t)e * CHN + ch0], part);
    part = fmaf(h1, Wc2[(size_t)e * CHN + ch1], part);
  }
  part += __shfl_xor(part, 16);
  part += __shfl_xor(part, 32);
  if (q == 0 && local < rows_c) {
    float cv = 1.f / (1.f + expf(-(part + bc2[e])));
    cw[ent] = wts[(size_t)(ent >> 2) * EE + e] * cv;
  }
}

// ---------------------------------------------------------------------------
// Combine: out[t] = sum_s cw*o / (sum_s cw + eps)
// ---------------------------------------------------------------------------
__global__ __launch_bounds__(256)
void k_combine(const float* __restrict__ o_p, const float* __restrict__ cw,
               float* __restrict__ out) {
  int gid = blockIdx.x * 256 + threadIdx.x;
  int t = gid >> 7;
  int j = gid & 127;
  float c0 = cw[t * 4 + 0], c1 = cw[t * 4 + 1];
  float c2 = cw[t * 4 + 2], c3 = cw[t * 4 + 3];
  float den = c0 + c1 + c2 + c3 + 1e-6f;
  const float4* base = reinterpret_cast<const float4*>(o_p) + (size_t)t * 4 * 128;
  float4 v0 = base[0 * 128 + j];
  float4 v1 = base[1 * 128 + j];
  float4 v2 = base[2 * 128 + j];
  float4 v3 = base[3 * 128 + j];
  float4 r;
  r.x = (c0 * v0.x + c1 * v1.x + c2 * v2.x + c3 * v3.x) / den;
  r.y = (c0 * v0.y + c1 * v1.y + c2 * v2.y + c3 * v3.y) / den;
  r.z = (c0 * v0.z + c1 * v1.z + c2 * v2.z + c3 * v3.z) / den;
  r.w = (c0 * v0.w + c1 * v1.w + c2 * v2.w + c3 * v3.w) / den;
  reinterpret_cast<float4*>(out)[gid] = r;
}

extern "C" void kernel_launch(void* const* d_in, const int* in_sizes, int n_in,
                              void* d_out, int out_size, void* d_ws, size_t ws_size,
                              hipStream_t stream) {
  const float* x   = (const float*)d_in[0];
  const float* W1  = (const float*)d_in[1];
  const float* b1  = (const float*)d_in[2];
  const float* W2  = (const float*)d_in[3];
  const float* b2  = (const float*)d_in[4];
  const float* Wg1 = (const float*)d_in[5];
  const float* bg1 = (const float*)d_in[6];
  const float* Wg2 = (const float*)d_in[7];
  const float* bg2 = (const float*)d_in[8];
  const float* Wc1 = (const float*)d_in[9];
  const float* bc1 = (const float*)d_in[10];
  const float* Wc2 = (const float*)d_in[11];
  const float* bc2 = (const float*)d_in[12];
  float* out = (float*)d_out;

  // workspace layout (~64 MB)
  char* p = (char*)d_ws;
  u16* xb = (u16*)p;            p += (size_t)BT * DD * 2;            // 2 MB
  u32* img = (u32*)p;           p += (size_t)64 * 4 * 16 * 2048 * 4; // 32 MB
  float* h_g = (float*)p;                                            // gate h (4 MB)
  u32* hid = (u32*)p;           p += (size_t)MAXCH * 64 * DD * 2;    // 10 MB (aliases h_g; disjoint in time)
  float* wts = (float*)p;       p += (size_t)BT * EE * 4;            // 256 KB
  float* cw  = (float*)p;       p += (size_t)BT * KK * 4;            // 32 KB
  float* o_p = (float*)p;       p += (size_t)BT * KK * DD * 4;       // 16 MB
  int* cnt = (int*)p;           p += 256;
  int* tlist = (int*)p;         p += (size_t)EE * BT * 4;            // 256 KB
  int* chunk2e = (int*)p;       p += 1024;
  int* chunkloc = (int*)p;      p += 1024;
  u32* img_c = (u32*)p;         p += (size_t)EE * 16 * 512 * 4;      // 1 MB
  int* topi = (int*)p;          p += (size_t)BT * KK * 4;            // 32 KB

  k_prep<<<NB_PREP, 256, 0, stream>>>(x, W1, W2, Wc1, Wg1, bg1,
                                      xb, img, img_c, h_g);
  k_gate_route<<<BT / 8, 256, 0, stream>>>(h_g, Wg2, bg2, wts, topi);
  k_build<<<1, 1024, 0, stream>>>(topi, cnt, tlist, chunk2e, chunkloc);
  k_gemm1<<<dim3(MAXCH, 4), 256, 0, stream>>>(xb, img, b1, cnt, tlist,
                                              chunk2e, chunkloc, hid);
  k_gemm2<<<dim3(MAXCH, 4), 256, 0, stream>>>(hid, img, b2, cnt, tlist,
                                              chunk2e, chunkloc, o_p);
  k_conf2<<<MAXCH, 256, 0, stream>>>(o_p, img_c, bc1, Wc2, bc2, wts,
                                     cnt, tlist, chunk2e, chunkloc, cw);
  k_combine<<<(BT * (DD / 4)) / 256, 256, 0, stream>>>(o_p, cw, out);
}

// Round 13
// 105.574 us; speedup vs baseline: 1.5610x; 1.5610x over previous
//
#include <hip/hip_runtime.h>
#include <hip/hip_bf16.h>

// Problem constants
#define BT 2048   // batch
#define DD 512    // input dim
#define HH 512    // hidden dim
#define EE 32     // experts
#define KK 4      // top-k
#define CHN 32    // confidence hidden
#define MAXCH 160 // max 64-row chunks: 8192/64 + 32

// prep (pure streaming): cvt_x (512) | tr_wc (256) | tr_w (66 z-images x 32)
#define NB_CVT 512
#define NB_TRWC 256
#define NB_TRW 2112
#define NB_PREP (NB_CVT + NB_TRWC + NB_TRW)

typedef unsigned int u32;
typedef unsigned short u16;
typedef __attribute__((ext_vector_type(8))) short short8;
typedef __attribute__((ext_vector_type(4))) float f32x4;
typedef __attribute__((ext_vector_type(2))) u32 u32x2;
typedef __attribute__((ext_vector_type(4))) u32 u32x4;

__device__ inline u16 f2bf(float f) {  // RNE float->bf16
  u32 u = __builtin_bit_cast(u32, f);
  u32 r = (u + 0x7FFFu + ((u >> 16) & 1u)) >> 16;
  return (u16)r;
}
__device__ inline float bf16f(u16 b) {  // bf16 -> float
  u32 u = ((u32)b) << 16;
  return __builtin_bit_cast(float, u);
}
__device__ inline u32 pack2bf(float a, float b) {
  return (u32)f2bf(a) | ((u32)f2bf(b) << 16);
}
__device__ inline void gload_lds16(const u32* g, u32* l) {
  __builtin_amdgcn_global_load_lds((const __attribute__((address_space(1))) u32*)g,
                                   (__attribute__((address_space(3))) u32*)l, 16, 0, 0);
}

// ---------------------------------------------------------------------------
// Fused prep (pure streaming, no LDS):
//  cvt_x: x -> bf16 hi (xh) + bf16 residual lo (xl = bf16(x - float(hi)))
//  tr_wc: Wc1 conf image
//  tr_w:  z 0..31 W1 | 32..63 W2 | 64 Wg1-hi | 65 Wg1-lo  -> fraglet images
// ---------------------------------------------------------------------------
__global__ __launch_bounds__(256)
void k_prep(const float* __restrict__ x, const float* __restrict__ W1,
            const float* __restrict__ W2, const float* __restrict__ Wc1,
            const float* __restrict__ Wg1,
            u16* __restrict__ xh, u16* __restrict__ xl,
            u32* __restrict__ img, u32* __restrict__ img_c) {
  const int bx = blockIdx.x;
  const int tid = threadIdx.x;
  if (bx < NB_CVT) {
    // ---- cvt_x: hi + residual-lo ----
    int gid = bx * 256 + tid;
    const float4* src = reinterpret_cast<const float4*>(x) + (size_t)gid * 2;
    float4 a = src[0], b = src[1];
    u32x4 hi = { pack2bf(a.x, a.y), pack2bf(a.z, a.w),
                 pack2bf(b.x, b.y), pack2bf(b.z, b.w) };
    float lx0 = a.x - bf16f(f2bf(a.x)), lx1 = a.y - bf16f(f2bf(a.y));
    float lx2 = a.z - bf16f(f2bf(a.z)), lx3 = a.w - bf16f(f2bf(a.w));
    float lx4 = b.x - bf16f(f2bf(b.x)), lx5 = b.y - bf16f(f2bf(b.y));
    float lx6 = b.z - bf16f(f2bf(b.z)), lx7 = b.w - bf16f(f2bf(b.w));
    u32x4 lo = { pack2bf(lx0, lx1), pack2bf(lx2, lx3),
                 pack2bf(lx4, lx5), pack2bf(lx6, lx7) };
    reinterpret_cast<u32x4*>(xh)[gid] = hi;
    reinterpret_cast<u32x4*>(xl)[gid] = lo;
  } else if (bx < NB_CVT + NB_TRWC) {
    // ---- tr_wc: Wc1 -> bf16 k-major fraglet image ----
    int idx = (bx - NB_CVT) * 2 + (tid >> 7);
    int e = idx >> 4, s = idx & 15;
    int t127 = tid & 127;
    int q = t127 >> 5, col = t127 & 31;
    const float* W = Wc1 + (size_t)e * DD * CHN;
    float v[8];
#pragma unroll
    for (int j = 0; j < 8; ++j)
      v[j] = W[(size_t)(s * 32 + q * 8 + j) * CHN + col];
    u32x4 fr = { pack2bf(v[0], v[1]), pack2bf(v[2], v[3]),
                 pack2bf(v[4], v[5]), pack2bf(v[6], v[7]) };
    *reinterpret_cast<u32x4*>(img_c + ((size_t)e * 16 + s) * 512 + q * 128 + col * 4) = fr;
  } else {
    // ---- tr_w: weight fraglet images (incl. Wg1 hi/lo at z=64/65) ----
    int u = bx - (NB_CVT + NB_TRWC);
    int z = u >> 5;
    int s = (u >> 1) & 15;
    int n = (u & 1) * 256 + tid;
    const float* W = (z < EE) ? (W1 + (size_t)z * DD * HH)
                   : (z < 2 * EE) ? (W2 + (size_t)(z - EE) * HH * DD)
                   : Wg1;
    float v[32];
#pragma unroll
    for (int k = 0; k < 32; k++)
      v[k] = W[(size_t)(s * 32 + k) * 512 + n];
    if (z == 65) {
#pragma unroll
      for (int k = 0; k < 32; k++)
        v[k] = v[k] - bf16f(f2bf(v[k]));    // exact residual (Sterbenz)
    }
    int nc = n >> 7, coll = n & 127;
    u32* ob = img + ((size_t)(z * 4 + nc) * 16 + s) * 2048 + coll * 4;
#pragma unroll
    for (int g = 0; g < 4; g++) {
      u32x4 fr = { pack2bf(v[g * 8 + 0], v[g * 8 + 1]),
                   pack2bf(v[g * 8 + 2], v[g * 8 + 3]),
                   pack2bf(v[g * 8 + 4], v[g * 8 + 5]),
                   pack2bf(v[g * 8 + 6], v[g * 8 + 7]) };
      *reinterpret_cast<u32x4*>(ob + g * 512) = fr;
    }
  }
}

// ---------------------------------------------------------------------------
// Gate hidden via MFMA with exact-split bf16 (4 cross terms = fp32-accurate):
// hidT = Wg1T . xT. Grid (32 chunks, 8 h-chunks), 256 thr (4 waves).
// Per block: 64h x 64t, K=512 in 16 steps of 32, dbuf-staged hi/lo images.
// ---------------------------------------------------------------------------
__global__ __launch_bounds__(256)
void k_gate_mfma(const u16* __restrict__ xh, const u16* __restrict__ xl,
                 const u32* __restrict__ img, const float* __restrict__ bg1,
                 float* __restrict__ h) {
  __shared__ u32 stg[2][2][1024];   // 16 KB: dbuf x {hi,lo} x (4k-grp x 64col x 4)
  const int chunk = blockIdx.x;     // 0..31
  const int hc = blockIdx.y;        // 0..7
  const int tid = threadIdx.x;
  const int w = tid >> 6, lane = tid & 63;
  const int l15 = lane & 15, q = lane >> 4;
  const int wm = w & 1, wn = w >> 1;
  const int nc = hc >> 1, co = (hc & 1) * 64;
  const u32* imgh = img + ((size_t)(64 * 4 + nc) * 16) * 2048;
  const u32* imgl = img + ((size_t)(65 * 4 + nc) * 16) * 2048;
  const int sq = tid >> 6, scol = tid & 63;
  auto stage = [&](int s, int b) {
    gload_lds16(imgh + s * 2048 + sq * 512 + (co + scol) * 4, stg[b][0] + tid * 4);
    gload_lds16(imgl + s * 2048 + sq * 512 + (co + scol) * 4, stg[b][1] + tid * 4);
  };
  const int t0 = chunk * 64 + wn * 32 + l15;
  const int t1 = t0 + 16;
  auto ldb = [&](const u16* src, int t, int s) {
    return *reinterpret_cast<const short8*>(src + (size_t)t * 512 + s * 32 + q * 8);
  };

  f32x4 acc[2][2];
#pragma unroll
  for (int a = 0; a < 2; a++)
#pragma unroll
    for (int b = 0; b < 2; b++) acc[a][b] = {0.f, 0.f, 0.f, 0.f};

  stage(0, 0);
  short8 bh[2], bl[2];
  bh[0] = ldb(xh, t0, 0); bh[1] = ldb(xh, t1, 0);
  bl[0] = ldb(xl, t0, 0); bl[1] = ldb(xl, t1, 0);
  __syncthreads();   // stage(0) drained

  for (int s = 0; s < 16; ++s) {
    const u32* ch = stg[s & 1][0];
    const u32* cl = stg[s & 1][1];
    short8 nh[2], nl[2];
    if (s < 15) {
      stage(s + 1, (s + 1) & 1);
      nh[0] = ldb(xh, t0, s + 1); nh[1] = ldb(xh, t1, s + 1);
      nl[0] = ldb(xl, t0, s + 1); nl[1] = ldb(xl, t1, s + 1);
    }
#pragma unroll
    for (int mf = 0; mf < 2; ++mf) {
      int col = wm * 32 + mf * 16 + l15;
      short8 ah = *reinterpret_cast<const short8*>(ch + q * 256 + col * 4);
      short8 al = *reinterpret_cast<const short8*>(cl + q * 256 + col * 4);
#pragma unroll
      for (int nf = 0; nf < 2; ++nf) {
        acc[mf][nf] = __builtin_amdgcn_mfma_f32_16x16x32_bf16(ah, bh[nf], acc[mf][nf], 0, 0, 0);
        acc[mf][nf] = __builtin_amdgcn_mfma_f32_16x16x32_bf16(ah, bl[nf], acc[mf][nf], 0, 0, 0);
        acc[mf][nf] = __builtin_amdgcn_mfma_f32_16x16x32_bf16(al, bh[nf], acc[mf][nf], 0, 0, 0);
        acc[mf][nf] = __builtin_amdgcn_mfma_f32_16x16x32_bf16(al, bl[nf], acc[mf][nf], 0, 0, 0);
      }
    }
    __syncthreads();   // stage(s+1) drained; cur reads done
    if (s < 15) {
      bh[0] = nh[0]; bh[1] = nh[1];
      bl[0] = nl[0]; bl[1] = nl[1];
    }
  }

  // epilogue: bias + relu -> h fp32
#pragma unroll
  for (int mf = 0; mf < 2; ++mf) {
    int hcol = hc * 64 + wm * 32 + mf * 16 + q * 4;
    float4 bb = *reinterpret_cast<const float4*>(&bg1[hcol]);
#pragma unroll
    for (int nf = 0; nf < 2; ++nf) {
      int t = chunk * 64 + wn * 32 + nf * 16 + l15;
      float4 o;
      o.x = fmaxf(acc[mf][nf].x + bb.x, 0.f);
      o.y = fmaxf(acc[mf][nf].y + bb.y, 0.f);
      o.z = fmaxf(acc[mf][nf].z + bb.z, 0.f);
      o.w = fmaxf(acc[mf][nf].w + bb.w, 0.f);
      *reinterpret_cast<float4*>(&h[(size_t)t * HH + hcol]) = o;
    }
  }
}

// ---------------------------------------------------------------------------
// Gating logits + softmax + top-4. 8 tokens/block, 256 thr. NO atomics.
// ---------------------------------------------------------------------------
__global__ __launch_bounds__(256)
void k_gate_route(const float* __restrict__ h, const float* __restrict__ Wg2,
                  const float* __restrict__ bg2, float* __restrict__ wts,
                  int* __restrict__ topi) {
  __shared__ float wg2s[HH * EE];  // 64 KB, k-major [512][32]
  __shared__ float hb[8][HH];      // 16 KB
  const int tid = threadIdx.x;
  const int t0 = blockIdx.x * 8;
#pragma unroll
  for (int i = 0; i < 16; ++i) {
    int idx = tid + i * 256;
    reinterpret_cast<float4*>(wg2s)[idx] =
        reinterpret_cast<const float4*>(Wg2)[idx];
  }
  for (int idx = tid; idx < 8 * 128; idx += 256) {
    int m = idx >> 7, j = idx & 127;
    *reinterpret_cast<float4*>(&hb[m][4 * j]) =
        *reinterpret_cast<const float4*>(&h[(size_t)(t0 + m) * HH + 4 * j]);
  }
  __syncthreads();
  const int lane = tid & 63, wv = tid >> 6;
  const int e = lane & 31, th = lane >> 5;
  const int lt = wv * 2 + th;          // local token 0..7
  const int t = t0 + lt;
  float ac[4] = {0.f, 0.f, 0.f, 0.f};
  for (int k0 = 0; k0 < HH; k0 += 8) {
    float4 h0 = *reinterpret_cast<const float4*>(&hb[lt][k0]);
    float4 h1 = *reinterpret_cast<const float4*>(&hb[lt][k0 + 4]);
    float hv[8] = {h0.x, h0.y, h0.z, h0.w, h1.x, h1.y, h1.z, h1.w};
#pragma unroll
    for (int u = 0; u < 8; ++u)
      ac[u & 3] = fmaf(hv[u], wg2s[(k0 + u) * EE + e], ac[u & 3]);
  }
  float logit = ((ac[0] + ac[1]) + (ac[2] + ac[3])) + bg2[e];
  float mx = logit;
#pragma unroll
  for (int m = 16; m >= 1; m >>= 1) mx = fmaxf(mx, __shfl_xor(mx, m, 32));
  float ex = expf(logit - mx);
  float sm = ex;
#pragma unroll
  for (int m = 16; m >= 1; m >>= 1) sm += __shfl_xor(sm, m, 32);
  float w = ex / sm;
  wts[(size_t)t * EE + e] = w;
  float wcur = w;
  for (int j = 0; j < KK; j++) {
    float v = wcur;
    int vi = e;
#pragma unroll
    for (int m = 16; m >= 1; m >>= 1) {
      float ov = __shfl_xor(v, m, 32);
      int oi = __shfl_xor(vi, m, 32);
      if (ov > v || (ov == v && oi < vi)) { v = ov; vi = oi; }
    }
    if (e == 0) topi[(t << 2) | j] = vi;
    if (e == vi) wcur = -1.f;
  }
}

// ---------------------------------------------------------------------------
// Build routing lists + chunk tables from topi. One block, 1024 thr.
// ---------------------------------------------------------------------------
__global__ __launch_bounds__(1024)
void k_build(const int* __restrict__ topi, int* __restrict__ cnt,
             int* __restrict__ tlist, int* __restrict__ chunk2e,
             int* __restrict__ chunkloc) {
  __shared__ int lcnt[EE];
  const int tid = threadIdx.x;
  if (tid < EE) lcnt[tid] = 0;
  __syncthreads();
  for (int i = tid; i < BT * KK; i += 1024) {
    int e = topi[i];
    int pos = atomicAdd(&lcnt[e], 1);
    tlist[(size_t)e * BT + pos] = i;
  }
  __syncthreads();
  if (tid < EE) {
    int e = tid;
    cnt[e] = lcnt[e];
    int off = 0, tot = 0;
    for (int j = 0; j < EE; ++j) {
      int nj = (lcnt[j] + 63) >> 6;
      if (j < e) off += nj;
      tot += nj;
    }
    int myn = (lcnt[e] + 63) >> 6;
    for (int j = 0; j < myn; ++j) {
      chunk2e[off + j] = e; chunkloc[off + j] = j;
    }
    for (int idx = tot + e; idx < MAXCH; idx += EE) {
      chunk2e[idx] = -1; chunkloc[idx] = 0;
    }
  }
}

// XCD-affinity chunk remap.
__device__ inline int remap_chunk(int bx) {
  return (bx & 7) * (MAXCH / 8) + (bx >> 3);
}

// ---------------------------------------------------------------------------
// GEMM1 (grouped, swapped): hidT = W1T(512h x 512k) . xT(512k x 64t).
// ---------------------------------------------------------------------------
__global__ __launch_bounds__(256)
void k_gemm1(const u16* __restrict__ xb, const u32* __restrict__ img,
             const float* __restrict__ b1, const int* __restrict__ cnt,
             const int* __restrict__ tlist, const int* __restrict__ chunk2e,
             const int* __restrict__ chunkloc, u32* __restrict__ hid) {
  __shared__ u32 stg[2][4096];   // 2 x 16 KB
  __shared__ int tkl[64];
  const int c = remap_chunk(blockIdx.x);
  const int e = chunk2e[c];
  if (e < 0) return;
  const int hc = blockIdx.y;
  const int loc = chunkloc[c];
  const int nt = cnt[e];
  const int tid = threadIdx.x;
  const int w = tid >> 6, lane = tid & 63;
  const int l15 = lane & 15, q = lane >> 4;
  const int wm = w & 1, wn = w >> 1;

  const u32* imgb = img + ((size_t)(e * 4 + hc) * 16) * 2048;
  auto stage = [&](int st, u32* dst) {
    const u32* src = imgb + st * 4096;
#pragma unroll
    for (int i = 0; i < 4; i++)
      gload_lds16(src + tid * 4 + i * 1024, dst + tid * 4 + i * 1024);
  };

  stage(0, stg[0]);
  if (tid < 64) {
    int i = min(loc * 64 + tid, nt - 1);
    tkl[tid] = tlist[(size_t)e * BT + i] >> 2;
  }
  __syncthreads();

  const int t0 = tkl[wn * 32 + l15];
  const int t1 = tkl[wn * 32 + 16 + l15];
  auto ldb = [&](int t, int st, int ss) {
    return *reinterpret_cast<const short8*>(
        xb + (size_t)t * 512 + st * 64 + ss * 32 + q * 8);
  };

  f32x4 acc[4][2];
#pragma unroll
  for (int a = 0; a < 4; a++)
#pragma unroll
    for (int b = 0; b < 2; b++) acc[a][b] = {0.f, 0.f, 0.f, 0.f};

  short8 bfr[2][2];
  bfr[0][0] = ldb(t0, 0, 0); bfr[0][1] = ldb(t0, 0, 1);
  bfr[1][0] = ldb(t1, 0, 0); bfr[1][1] = ldb(t1, 0, 1);

  for (int st = 0; st < 8; ++st) {
    const u32* cur = stg[st & 1];
    short8 nb[2][2];
    if (st < 7) {
      stage(st + 1, stg[(st + 1) & 1]);
      nb[0][0] = ldb(t0, st + 1, 0); nb[0][1] = ldb(t0, st + 1, 1);
      nb[1][0] = ldb(t1, st + 1, 0); nb[1][1] = ldb(t1, st + 1, 1);
    }
#pragma unroll
    for (int ss = 0; ss < 2; ++ss) {
#pragma unroll
      for (int mf = 0; mf < 4; ++mf) {
        int col = wm * 64 + mf * 16 + l15;
        short8 af = *reinterpret_cast<const short8*>(
            cur + ss * 2048 + q * 512 + col * 4);
        acc[mf][0] = __builtin_amdgcn_mfma_f32_16x16x32_bf16(af, bfr[0][ss], acc[mf][0], 0, 0, 0);
        acc[mf][1] = __builtin_amdgcn_mfma_f32_16x16x32_bf16(af, bfr[1][ss], acc[mf][1], 0, 0, 0);
      }
    }
    __syncthreads();
    if (st < 7) {
      bfr[0][0] = nb[0][0]; bfr[0][1] = nb[0][1];
      bfr[1][0] = nb[1][0]; bfr[1][1] = nb[1][1];
    }
  }

  const float* b1e = b1 + (size_t)e * HH;
#pragma unroll
  for (int mf = 0; mf < 4; ++mf) {
    int h0 = hc * 128 + wm * 64 + mf * 16 + q * 4;
    float4 bb = *reinterpret_cast<const float4*>(b1e + h0);
#pragma unroll
    for (int nf = 0; nf < 2; ++nf) {
      int local = wn * 32 + nf * 16 + l15;
      int prow = c * 64 + local;
      float v0 = fmaxf(acc[mf][nf].x + bb.x, 0.f);
      float v1 = fmaxf(acc[mf][nf].y + bb.y, 0.f);
      float v2 = fmaxf(acc[mf][nf].z + bb.z, 0.f);
      float v3 = fmaxf(acc[mf][nf].w + bb.w, 0.f);
      u32x2 pk = { pack2bf(v0, v1), pack2bf(v2, v3) };
      *reinterpret_cast<u32x2*>(hid + (size_t)prow * 256 + (h0 >> 1)) = pk;
    }
  }
}

// ---------------------------------------------------------------------------
// GEMM2 (grouped, swapped): oT = W2T(512d x 512h) . hidT(512h x 64t).
// ---------------------------------------------------------------------------
__global__ __launch_bounds__(256)
void k_gemm2(const u32* __restrict__ hid, const u32* __restrict__ img,
             const float* __restrict__ b2, const int* __restrict__ cnt,
             const int* __restrict__ tlist, const int* __restrict__ chunk2e,
             const int* __restrict__ chunkloc, float* __restrict__ o_p) {
  __shared__ u32 stg[2][4096];
  __shared__ int tke[64];
  const int c = remap_chunk(blockIdx.x);
  const int e = chunk2e[c];
  if (e < 0) return;
  const int dc = blockIdx.y;
  const int loc = chunkloc[c];
  const int nt = cnt[e];
  const int tid = threadIdx.x;
  const int w = tid >> 6, lane = tid & 63;
  const int l15 = lane & 15, q = lane >> 4;
  const int wm = w & 1, wn = w >> 1;
  const int rows_c = min(64, nt - loc * 64);

  const u32* imgb = img + ((size_t)((EE + e) * 4 + dc) * 16) * 2048;
  auto stage = [&](int st, u32* dst) {
    const u32* src = imgb + st * 4096;
#pragma unroll
    for (int i = 0; i < 4; i++)
      gload_lds16(src + tid * 4 + i * 1024, dst + tid * 4 + i * 1024);
  };

  stage(0, stg[0]);
  if (tid < 64) {
    int i = min(loc * 64 + tid, nt - 1);
    tke[tid] = tlist[(size_t)e * BT + i];
  }
  __syncthreads();

  const u16* hid16 = (const u16*)hid;
  const int pr0 = c * 64 + wn * 32 + l15;
  const int pr1 = pr0 + 16;
  auto ldb = [&](int pr, int st, int ss) {
    return *reinterpret_cast<const short8*>(
        hid16 + (size_t)pr * 512 + st * 64 + ss * 32 + q * 8);
  };

  f32x4 acc[4][2];
#pragma unroll
  for (int a = 0; a < 4; a++)
#pragma unroll
    for (int b = 0; b < 2; b++) acc[a][b] = {0.f, 0.f, 0.f, 0.f};

  short8 bfr[2][2];
  bfr[0][0] = ldb(pr0, 0, 0); bfr[0][1] = ldb(pr0, 0, 1);
  bfr[1][0] = ldb(pr1, 0, 0); bfr[1][1] = ldb(pr1, 0, 1);

  for (int st = 0; st < 8; ++st) {
    const u32* cur = stg[st & 1];
    short8 nb[2][2];
    if (st < 7) {
      stage(st + 1, stg[(st + 1) & 1]);
      nb[0][0] = ldb(pr0, st + 1, 0); nb[0][1] = ldb(pr0, st + 1, 1);
      nb[1][0] = ldb(pr1, st + 1, 0); nb[1][1] = ldb(pr1, st + 1, 1);
    }
#pragma unroll
    for (int ss = 0; ss < 2; ++ss) {
#pragma unroll
      for (int mf = 0; mf < 4; ++mf) {
        int col = wm * 64 + mf * 16 + l15;
        short8 af = *reinterpret_cast<const short8*>(
            cur + ss * 2048 + q * 512 + col * 4);
        acc[mf][0] = __builtin_amdgcn_mfma_f32_16x16x32_bf16(af, bfr[0][ss], acc[mf][0], 0, 0, 0);
        acc[mf][1] = __builtin_amdgcn_mfma_f32_16x16x32_bf16(af, bfr[1][ss], acc[mf][1], 0, 0, 0);
      }
    }
    __syncthreads();
    if (st < 7) {
      bfr[0][0] = nb[0][0]; bfr[0][1] = nb[0][1];
      bfr[1][0] = nb[1][0]; bfr[1][1] = nb[1][1];
    }
  }

  const float* b2e = b2 + (size_t)e * DD;
#pragma unroll
  for (int mf = 0; mf < 4; ++mf) {
    int d0 = dc * 128 + wm * 64 + mf * 16 + q * 4;
    float4 bb = *reinterpret_cast<const float4*>(b2e + d0);
#pragma unroll
    for (int nf = 0; nf < 2; ++nf) {
      int local = wn * 32 + nf * 16 + l15;
      if (local < rows_c) {
        int ent = tke[local];
        int t = ent >> 2, sl = ent & 3;
        float4 v;
        v.x = acc[mf][nf].x + bb.x;
        v.y = acc[mf][nf].y + bb.y;
        v.z = acc[mf][nf].z + bb.z;
        v.w = acc[mf][nf].w + bb.w;
        *reinterpret_cast<float4*>(&o_p[((size_t)t * KK + sl) * DD + d0]) = v;
      }
    }
  }
}

// ---------------------------------------------------------------------------
// Confidence via MFMA. One block per 64-token chunk, 256 thr (4 waves).
// ---------------------------------------------------------------------------
__global__ __launch_bounds__(256)
void k_conf2(const float* __restrict__ o_p, const u32* __restrict__ img_c,
             const float* __restrict__ bc1, const float* __restrict__ Wc2,
             const float* __restrict__ bc2, const float* __restrict__ wts,
             const int* __restrict__ cnt, const int* __restrict__ tlist,
             const int* __restrict__ chunk2e, const int* __restrict__ chunkloc,
             float* __restrict__ cw) {
  __shared__ u32 stg[8192];
  __shared__ int tke[64];
  const int c = remap_chunk(blockIdx.x);
  const int e = chunk2e[c];
  if (e < 0) return;
  const int loc = chunkloc[c];
  const int nt = cnt[e];
  const int tid = threadIdx.x;
  const int w = tid >> 6, lane = tid & 63;
  const int l15 = lane & 15, q = lane >> 4;

  const u32* src = img_c + (size_t)e * 16 * 512;
#pragma unroll
  for (int i = 0; i < 8; ++i)
    gload_lds16(src + tid * 4 + i * 1024, stg + tid * 4 + i * 1024);
  if (tid < 64) {
    int i = min(loc * 64 + tid, nt - 1);
    tke[tid] = tlist[(size_t)e * BT + i];
  }
  __syncthreads();

  const int rows_c = min(64, nt - loc * 64);
  const int local = w * 16 + l15;
  const int ent = tke[local];
  const float* orow = o_p + (size_t)ent * DD;

  f32x4 acc0 = {0.f, 0.f, 0.f, 0.f}, acc1 = {0.f, 0.f, 0.f, 0.f};
#pragma unroll
  for (int st = 0; st < 16; ++st) {
    float4 f0 = *reinterpret_cast<const float4*>(orow + st * 32 + q * 8);
    float4 f1 = *reinterpret_cast<const float4*>(orow + st * 32 + q * 8 + 4);
    u32x4 bp = { pack2bf(f0.x, f0.y), pack2bf(f0.z, f0.w),
                 pack2bf(f1.x, f1.y), pack2bf(f1.z, f1.w) };
    short8 bfrag = __builtin_bit_cast(short8, bp);
    short8 af0 = *reinterpret_cast<const short8*>(
        stg + st * 512 + q * 128 + l15 * 4);
    short8 af1 = *reinterpret_cast<const short8*>(
        stg + st * 512 + q * 128 + (16 + l15) * 4);
    acc0 = __builtin_amdgcn_mfma_f32_16x16x32_bf16(af0, bfrag, acc0, 0, 0, 0);
    acc1 = __builtin_amdgcn_mfma_f32_16x16x32_bf16(af1, bfrag, acc1, 0, 0, 0);
  }

  float part = 0.f;
#pragma unroll
  for (int i = 0; i < 4; ++i) {
    int ch0 = q * 4 + i, ch1 = 16 + q * 4 + i;
    float h0 = fmaxf(acc0[i] + bc1[(size_t)e * CHN + ch0], 0.f);
    float h1 = fmaxf(acc1[i] + bc1[(size_t)e * CHN + ch1], 0.f);
    part = fmaf(h0, Wc2[(size_t)e * CHN + ch0], part);
    part = fmaf(h1, Wc2[(size_t)e * CHN + ch1], part);
  }
  part += __shfl_xor(part, 16);
  part += __shfl_xor(part, 32);
  if (q == 0 && local < rows_c) {
    float cv = 1.f / (1.f + expf(-(part + bc2[e])));
    cw[ent] = wts[(size_t)(ent >> 2) * EE + e] * cv;
  }
}

// ---------------------------------------------------------------------------
// Combine: out[t] = sum_s cw*o / (sum_s cw + eps)
// ---------------------------------------------------------------------------
__global__ __launch_bounds__(256)
void k_combine(const float* __restrict__ o_p, const float* __restrict__ cw,
               float* __restrict__ out) {
  int gid = blockIdx.x * 256 + threadIdx.x;
  int t = gid >> 7;
  int j = gid & 127;
  float c0 = cw[t * 4 + 0], c1 = cw[t * 4 + 1];
  float c2 = cw[t * 4 + 2], c3 = cw[t * 4 + 3];
  float den = c0 + c1 + c2 + c3 + 1e-6f;
  const float4* base = reinterpret_cast<const float4*>(o_p) + (size_t)t * 4 * 128;
  float4 v0 = base[0 * 128 + j];
  float4 v1 = base[1 * 128 + j];
  float4 v2 = base[2 * 128 + j];
  float4 v3 = base[3 * 128 + j];
  float4 r;
  r.x = (c0 * v0.x + c1 * v1.x + c2 * v2.x + c3 * v3.x) / den;
  r.y = (c0 * v0.y + c1 * v1.y + c2 * v2.y + c3 * v3.y) / den;
  r.z = (c0 * v0.z + c1 * v1.z + c2 * v2.z + c3 * v3.z) / den;
  r.w = (c0 * v0.w + c1 * v1.w + c2 * v2.w + c3 * v3.w) / den;
  reinterpret_cast<float4*>(out)[gid] = r;
}

extern "C" void kernel_launch(void* const* d_in, const int* in_sizes, int n_in,
                              void* d_out, int out_size, void* d_ws, size_t ws_size,
                              hipStream_t stream) {
  const float* x   = (const float*)d_in[0];
  const float* W1  = (const float*)d_in[1];
  const float* b1  = (const float*)d_in[2];
  const float* W2  = (const float*)d_in[3];
  const float* b2  = (const float*)d_in[4];
  const float* Wg1 = (const float*)d_in[5];
  const float* bg1 = (const float*)d_in[6];
  const float* Wg2 = (const float*)d_in[7];
  const float* bg2 = (const float*)d_in[8];
  const float* Wc1 = (const float*)d_in[9];
  const float* bc1 = (const float*)d_in[10];
  const float* Wc2 = (const float*)d_in[11];
  const float* bc2 = (const float*)d_in[12];
  float* out = (float*)d_out;

  // workspace layout (~63 MB)
  char* p = (char*)d_ws;
  u16* xh = (u16*)p;            p += (size_t)BT * DD * 2;            // 2 MB
  u32* img = (u32*)p;           p += (size_t)66 * 4 * 16 * 2048 * 4; // 33 MB (64 expert + 2 gate imgs)
  float* h_g = (float*)p;                                            // h fp32 (4 MB)
  u16* xl = (u16*)(p + (size_t)4 * 1024 * 1024);                     // x residual (2 MB, after h)
  u32* hid = (u32*)p;           p += (size_t)MAXCH * 64 * DD * 2;    // 10.5 MB (aliases h_g+xl; disjoint in time)
  float* wts = (float*)p;       p += (size_t)BT * EE * 4;            // 256 KB
  float* cw  = (float*)p;       p += (size_t)BT * KK * 4;            // 32 KB
  float* o_p = (float*)p;       p += (size_t)BT * KK * DD * 4;       // 16 MB
  int* cnt = (int*)p;           p += 256;
  int* tlist = (int*)p;         p += (size_t)EE * BT * 4;            // 256 KB
  int* chunk2e = (int*)p;       p += 1024;
  int* chunkloc = (int*)p;      p += 1024;
  u32* img_c = (u32*)p;         p += (size_t)EE * 16 * 512 * 4;      // 1 MB
  int* topi = (int*)p;          p += (size_t)BT * KK * 4;            // 32 KB

  k_prep<<<NB_PREP, 256, 0, stream>>>(x, W1, W2, Wc1, Wg1,
                                      xh, xl, img, img_c);
  k_gate_mfma<<<dim3(32, 8), 256, 0, stream>>>(xh, xl, img, bg1, h_g);
  k_gate_route<<<BT / 8, 256, 0, stream>>>(h_g, Wg2, bg2, wts, topi);
  k_build<<<1, 1024, 0, stream>>>(topi, cnt, tlist, chunk2e, chunkloc);
  k_gemm1<<<dim3(MAXCH, 4), 256, 0, stream>>>(xh, img, b1, cnt, tlist,
                                              chunk2e, chunkloc, hid);
  k_gemm2<<<dim3(MAXCH, 4), 256, 0, stream>>>(hid, img, b2, cnt, tlist,
                                              chunk2e, chunkloc, o_p);
  k_conf2<<<MAXCH, 256, 0, stream>>>(o_p, img_c, bc1, Wc2, bc2, wts,
                                     cnt, tlist, chunk2e, chunkloc, cw);
  k_combine<<<(BT * (DD / 4)) / 256, 256, 0, stream>>>(o_p, cw, out);
}